// Round 14
// baseline (55.040 us; speedup 1.0000x reference)
//
#include <hip/hip_runtime.h>

typedef unsigned short u16;
typedef __attribute__((ext_vector_type(8))) short bf16x8;
typedef __attribute__((ext_vector_type(4))) float f32x4;

__device__ __forceinline__ u16 f2bf(float f) {
  union { float f; unsigned u; } v; v.f = f;
  unsigned u = v.u;
  return (u16)((u + 0x7FFFu + ((u >> 16) & 1u)) >> 16);
}

__device__ __forceinline__ void gld16(const void* g, void* l) {
  __builtin_amdgcn_global_load_lds((const __attribute__((address_space(1))) void*)g,
                                   (__attribute__((address_space(3))) void*)l, 16, 0, 0);
}

// ---------------- fused prep: cvt x->bf16 | transpose+cvt w_qkv | w_out ----------------
__device__ __forceinline__ void tconv64(const float* __restrict__ in, u16* __restrict__ out,
                                        int R, int C, int bc, int br, float* t) {
  const int tid = threadIdx.x;
  const int c0 = bc * 64, r0 = br * 64;
  const int hi = tid >> 4, lo = tid & 15;
#pragma unroll
  for (int it = 0; it < 4; ++it) {
    int r = it * 16 + hi;
    float4 f = *(const float4*)&in[(size_t)(r0 + r) * C + c0 + lo * 4];
    float* tr = &t[r * 65 + lo * 4];
    tr[0] = f.x; tr[1] = f.y; tr[2] = f.z; tr[3] = f.w;
  }
  __syncthreads();
#pragma unroll
  for (int it = 0; it < 4; ++it) {
    int cc = it * 16 + hi;
    ushort4 o;
    o.x = f2bf(t[(lo * 4 + 0) * 65 + cc]);
    o.y = f2bf(t[(lo * 4 + 1) * 65 + cc]);
    o.z = f2bf(t[(lo * 4 + 2) * 65 + cc]);
    o.w = f2bf(t[(lo * 4 + 3) * 65 + cc]);
    *(ushort4*)&out[(size_t)(c0 + cc) * R + r0 + lo * 4] = o;
  }
}

__global__ __launch_bounds__(256) void prep(const float* __restrict__ x, u16* __restrict__ xb,
                                            const float* __restrict__ wq, u16* __restrict__ wqT,
                                            const float* __restrict__ wo, u16* __restrict__ woT) {
  __shared__ float t[64 * 65];
  int b = blockIdx.x;
  if (b < 1024) {
    int i = (b * 256 + threadIdx.x) * 8;
    float4 f0 = *(const float4*)(x + i);
    float4 f1 = *(const float4*)(x + i + 4);
    ushort4 r0, r1;
    r0.x = f2bf(f0.x); r0.y = f2bf(f0.y); r0.z = f2bf(f0.z); r0.w = f2bf(f0.w);
    r1.x = f2bf(f1.x); r1.y = f2bf(f1.y); r1.z = f2bf(f1.z); r1.w = f2bf(f1.w);
    *(ushort4*)(xb + i) = r0;
    *(ushort4*)(xb + i + 4) = r1;
  } else if (b < 1024 + 768) {
    int b2 = b - 1024;
    tconv64(wq, wqT, 1024, 3072, b2 % 48, b2 / 48, t);
  } else {
    int b3 = b - 1792;
    tconv64(wo, woT, 1024, 1024, b3 & 15, b3 >> 4, t);
  }
}

// ---- shared STAGE/COMPUTE macros for the dbuf GEMMs (BK=64, 4 waves 2x2) ----
#define GEMM_STAGE(As, Bs, A, BT, buf, kt, BM, BN, MT, NT)                        \
  {                                                                               \
    _Pragma("unroll")                                                             \
    for (int it = 0; it < MT; ++it) {                                             \
      int G = wv * (MT * 64) + it * 64 + lane;                                    \
      int r = G >> 3, g = G & 7, gs = g ^ (r & 7);                                \
      gld16(&A[(size_t)(m0 + r) * K + (kt) + gs * 8],                             \
            &As[buf][(wv * (MT * 64) + it * 64) * 8]);                            \
    }                                                                             \
    _Pragma("unroll")                                                             \
    for (int it = 0; it < NT; ++it) {                                             \
      int G = wv * (NT * 64) + it * 64 + lane;                                    \
      int r = G >> 3, g = G & 7, gs = g ^ (r & 7);                                \
      gld16(&BT[(size_t)(n0 + r) * K + (kt) + gs * 8],                            \
            &Bs[buf][(wv * (NT * 64) + it * 64) * 8]);                            \
    }                                                                             \
  }

#define GEMM_COMPUTE(As, Bs, buf, BM, BN, MT, NT)                                 \
  {                                                                               \
    _Pragma("unroll")                                                             \
    for (int ks = 0; ks < 2; ++ks) {                                              \
      bf16x8 av[MT], bv[NT];                                                      \
      _Pragma("unroll")                                                           \
      for (int m = 0; m < MT; ++m) {                                              \
        int r = wm * (BM / 2) + m * 16 + lr;                                      \
        av[m] = *(const bf16x8*)&As[buf][r * 64 + (((ks * 4 + lg) ^ (r & 7)) * 8)]; \
      }                                                                           \
      _Pragma("unroll")                                                           \
      for (int n = 0; n < NT; ++n) {                                              \
        int r = wn * (BN / 2) + n * 16 + lr;                                      \
        bv[n] = *(const bf16x8*)&Bs[buf][r * 64 + (((ks * 4 + lg) ^ (r & 7)) * 8)]; \
      }                                                                           \
      _Pragma("unroll")                                                           \
      for (int m = 0; m < MT; ++m)                                                \
        _Pragma("unroll")                                                         \
        for (int n = 0; n < NT; ++n)                                              \
          acc[m][n] = __builtin_amdgcn_mfma_f32_16x16x32_bf16(av[m], bv[n],       \
                                                              acc[m][n], 0, 0, 0); \
    }                                                                             \
  }

// ---------------- QKV GEMM (128x64) + fused V-transpose, XCD-swizzled ---------
// Isolated change vs R13: 1D grid 768, wg=(orig&7)*96+orig>>3 (bijective, 768=8*96).
// XCD k runs 96 consecutive wg = 2 m-strips x all 48 n -> A hot-set 512 KB stays
// L2-resident; A re-fetch 201 MB -> ~4 MB. Tiles/LDS/occupancy unchanged (48 KB, 3/CU).
__global__ __launch_bounds__(256) void gemm_qkv(const u16* __restrict__ A,
                                                const u16* __restrict__ BT,
                                                const float* __restrict__ bias,
                                                u16* __restrict__ qkv3,
                                                u16* __restrict__ vT,
                                                u16* __restrict__ vTs,
                                                int K) {
  constexpr int BM = 128, BN = 64, MT = 4, NT = 2;
  __shared__ u16 As[2][BM * 64];
  __shared__ u16 Bs[2][BN * 64];
  const int tid = threadIdx.x;
  const int lane = tid & 63, wv = tid >> 6;
  const int lr = lane & 15, lg = lane >> 4;
  const int wm = wv >> 1, wn = wv & 1;
  const int orig = blockIdx.x;
  const int wg = (orig & 7) * 96 + (orig >> 3);
  const int n0 = (wg % 48) * 64, m0 = (wg / 48) * 128;

  f32x4 acc[MT][NT] = {};

  GEMM_STAGE(As, Bs, A, BT, 0, 0, BM, BN, MT, NT);
  __syncthreads();
  int cur = 0;
  for (int kt = 64; kt < K; kt += 64) {
    GEMM_STAGE(As, Bs, A, BT, cur ^ 1, kt, BM, BN, MT, NT);
    GEMM_COMPUTE(As, Bs, cur, BM, BN, MT, NT);
    __syncthreads();
    cur ^= 1;
  }
  GEMM_COMPUTE(As, Bs, cur, BM, BN, MT, NT);

  if (n0 < 2048) {
#pragma unroll
    for (int m = 0; m < MT; ++m)
#pragma unroll
      for (int n = 0; n < NT; ++n) {
        int col = n0 + wn * 32 + n * 16 + lr;
        float bcol = bias[col];
#pragma unroll
        for (int qq = 0; qq < 4; ++qq) {
          int row = m0 + wm * 64 + m * 16 + 4 * lg + qq;
          qkv3[(size_t)row * 3072 + col] = f2bf(acc[m][n][qq] + bcol);
        }
      }
  } else {
    __syncthreads();               // all LDS reads of As/Bs done; reuse as T
    u16* T = &As[0][0];            // [64][132] bf16 (pad 132 spreads banks)
#pragma unroll
    for (int m = 0; m < MT; ++m)
#pragma unroll
      for (int n = 0; n < NT; ++n) {
        int col = wn * 32 + n * 16 + lr;
        float bcol = bias[n0 + col];
#pragma unroll
        for (int qq = 0; qq < 4; ++qq) {
          int row = wm * 64 + m * 16 + 4 * lg + qq;
          T[col * 132 + row] = f2bf(acc[m][n][qq] + bcol);
        }
      }
    __syncthreads();
    const int dgb = n0 - 2048;
#pragma unroll
    for (int c = wv; c < 64; c += 4) {
      uint val = (uint)T[c * 132 + lane * 2] | ((uint)T[c * 132 + lane * 2 + 1] << 16);
      *(uint*)&vT[(size_t)(dgb + c) * 2048 + m0 + lane * 2] = val;
    }
    {
      int rr = tid >> 6, c = tid & 63;
      vTs[(size_t)(dgb + c) * 64 + (m0 >> 5) + rr] = T[c * 132 + rr * 32];
    }
  }
}

// ---------------- out projection GEMM (64x64, f32 out, XCD-swizzled) ----------
// wg=(orig&7)*64+orig>>3 (bijective, 512=8*64): XCD k runs 4 m-strips x all 16 n
// -> A hot-set 512 KB L2-resident; A re-fetch 67 MB -> ~8 MB.
__global__ __launch_bounds__(256) void gemm_out(const u16* __restrict__ A,
                                                const u16* __restrict__ BT,
                                                const float* __restrict__ bias,
                                                float* __restrict__ Cp,
                                                int K) {
  constexpr int BM = 64, BN = 64, MT = 2, NT = 2;
  __shared__ u16 As[2][BM * 64];
  __shared__ u16 Bs[2][BN * 64];
  const int tid = threadIdx.x;
  const int lane = tid & 63, wv = tid >> 6;
  const int lr = lane & 15, lg = lane >> 4;
  const int wm = wv >> 1, wn = wv & 1;
  const int orig = blockIdx.x;
  const int wg = (orig & 7) * 64 + (orig >> 3);
  const int n0 = (wg & 15) * 64, m0 = (wg >> 4) * 64;

  f32x4 acc[MT][NT] = {};

  GEMM_STAGE(As, Bs, A, BT, 0, 0, BM, BN, MT, NT);
  __syncthreads();
  int cur = 0;
  for (int kt = 64; kt < K; kt += 64) {
    GEMM_STAGE(As, Bs, A, BT, cur ^ 1, kt, BM, BN, MT, NT);
    GEMM_COMPUTE(As, Bs, cur, BM, BN, MT, NT);
    __syncthreads();
    cur ^= 1;
  }
  GEMM_COMPUTE(As, Bs, cur, BM, BN, MT, NT);

#pragma unroll
  for (int m = 0; m < MT; ++m)
#pragma unroll
    for (int n = 0; n < NT; ++n) {
      int col = n0 + wn * 32 + n * 16 + lr;
      float bcol = bias[col];
#pragma unroll
      for (int qq = 0; qq < 4; ++qq) {
        int row = m0 + wm * 32 + m * 16 + 4 * lg + qq;
        Cp[(size_t)row * 1024 + col] = acc[m][n][qq] + bcol;
      }
    }
}

// ---------------- sparse attention: (head, 64-row) blocks, staged K/V ----------
// (unchanged from R13: P aliases K's LDS -> 64 KB, 2 blocks/CU)
__global__ __launch_bounds__(256) void sattn(const u16* __restrict__ qkv,
                                             const u16* __restrict__ vT,
                                             const u16* __restrict__ vTs,
                                             u16* __restrict__ ao) {
  const int h = blockIdx.x;
  const int i0b = blockIdx.y * 64;
  const int ws = i0b - 64;
  const int tid = threadIdx.x;
  const int lane = tid & 63, wv = tid >> 6;
  const int lr = lane & 15, lg = lane >> 4;

  __shared__ __attribute__((aligned(16))) u16 KP[256 * 64];   // 32 KB: K, then P
  __shared__ __attribute__((aligned(16))) u16 Vl[64 * 256];   // 32 KB

#pragma unroll
  for (int it = 0; it < 8; ++it) {
    {
      int ck = wv * 8 + it;
      int c = 8 * ck + (lane >> 3);
      int g = lane & 7, gs = g ^ (c & 7);
      int j = (c < 192) ? (ws + c) : ((c - 192) << 5);
      j = j < 0 ? 0 : (j > 2047 ? 2047 : j);
      gld16(&qkv[(size_t)j * 3072 + 1024 + h * 64 + gs * 8], &KP[ck * 512]);
    }
    {
      int tv = wv * 8 + it;
      int d = 2 * tv + (lane >> 5);
      int g = lane & 31, gs = g ^ (d & 7);
      const u16* src;
      if (gs < 24) {
        int c0 = ws + gs * 8;
        c0 = c0 < 0 ? 0 : (c0 > 2040 ? 2040 : c0);
        src = &vT[(size_t)(h * 64 + d) * 2048 + c0];
      } else {
        src = &vTs[(size_t)(h * 64 + d) * 64 + (gs - 24) * 8];
      }
      gld16(src, &Vl[tv * 512]);
    }
  }
  __syncthreads();

  const int i0 = i0b + wv * 16;
  const u16* qp = &qkv[(size_t)(i0 + lr) * 3072 + h * 64 + lg * 8];
  bf16x8 qa0 = *(const bf16x8*)qp;
  bf16x8 qa1 = *(const bf16x8*)(qp + 32);

  f32x4 sc[16];
#pragma unroll
  for (int n = 0; n < 16; ++n) {
    int c = n * 16 + lr;
    bf16x8 k0 = *(const bf16x8*)&KP[c * 64 + ((lg ^ (c & 7)) * 8)];
    bf16x8 k1 = *(const bf16x8*)&KP[c * 64 + (((4 + lg) ^ (c & 7)) * 8)];
    f32x4 a = {0.f, 0.f, 0.f, 0.f};
    a = __builtin_amdgcn_mfma_f32_16x16x32_bf16(qa0, k0, a, 0, 0, 0);
    a = __builtin_amdgcn_mfma_f32_16x16x32_bf16(qa1, k1, a, 0, 0, 0);
    sc[n] = a;
  }

  float mx[4] = {-1e30f, -1e30f, -1e30f, -1e30f};
#pragma unroll
  for (int n = 0; n < 16; ++n) {
    int c = n * 16 + lr;
    int jw = ws + c;
    int js = (c - 192) << 5;
    bool isw = c < 192;
#pragma unroll
    for (int qq = 0; qq < 4; ++qq) {
      int i = i0 + 4 * lg + qq;
      bool ok;
      if (isw) {
        int dd = i - jw; dd = dd < 0 ? -dd : dd;
        ok = (jw >= 0) && (jw < 2048) && ((dd <= 64) || ((jw & 31) == 0));
      } else {
        ok = (js < ws) || (js >= ws + 192);
      }
      float v = ok ? sc[n][qq] * 0.125f : -1e30f;
      sc[n][qq] = v;
      mx[qq] = fmaxf(mx[qq], v);
    }
  }
#pragma unroll
  for (int qq = 0; qq < 4; ++qq) {
    float v = mx[qq];
    v = fmaxf(v, __shfl_xor(v, 1));
    v = fmaxf(v, __shfl_xor(v, 2));
    v = fmaxf(v, __shfl_xor(v, 4));
    v = fmaxf(v, __shfl_xor(v, 8));
    mx[qq] = v;
  }

  __syncthreads();   // all waves finished reading K from KP -> safe to overwrite with P

  char* pw = (char*)KP + wv * 8192;
  float sm[4] = {0.f, 0.f, 0.f, 0.f};
#pragma unroll
  for (int n = 0; n < 16; ++n) {
#pragma unroll
    for (int qq = 0; qq < 4; ++qq) {
      float p = __expf(sc[n][qq] - mx[qq]);
      sm[qq] += p;
      int r = 4 * lg + qq, c = n * 16 + lr;
      *(u16*)(pw + r * 512 + ((2 * c) ^ ((r & 7) << 4))) = f2bf(p);
    }
  }
#pragma unroll
  for (int qq = 0; qq < 4; ++qq) {
    float s = sm[qq];
    s += __shfl_xor(s, 1);
    s += __shfl_xor(s, 2);
    s += __shfl_xor(s, 4);
    s += __shfl_xor(s, 8);
    sm[qq] = s;
  }

  f32x4 ov[4] = {{0.f,0.f,0.f,0.f},{0.f,0.f,0.f,0.f},{0.f,0.f,0.f,0.f},{0.f,0.f,0.f,0.f}};
#pragma unroll
  for (int ksb = 0; ksb < 8; ++ksb) {
    bf16x8 pa = *(const bf16x8*)(pw + lr * 512 + ((ksb * 64 + lg * 16) ^ ((lr & 7) << 4)));
#pragma unroll
    for (int n = 0; n < 4; ++n) {
      int d = n * 16 + lr;
      bf16x8 vb = *(const bf16x8*)&Vl[d * 256 + (((ksb * 4 + lg) ^ (d & 7)) * 8)];
      ov[n] = __builtin_amdgcn_mfma_f32_16x16x32_bf16(pa, vb, ov[n], 0, 0, 0);
    }
  }

#pragma unroll
  for (int qq = 0; qq < 4; ++qq) {
    float inv = 1.0f / sm[qq];
    int row = i0 + 4 * lg + qq;
#pragma unroll
    for (int n = 0; n < 4; ++n)
      ao[(size_t)row * 1024 + h * 64 + n * 16 + lr] = f2bf(ov[n][qq] * inv);
  }
}

// ---------------- launch ----------------
extern "C" void kernel_launch(void* const* d_in, const int* in_sizes, int n_in,
                              void* d_out, int out_size, void* d_ws, size_t ws_size,
                              hipStream_t stream) {
  (void)in_sizes; (void)n_in; (void)out_size; (void)ws_size;
  const float* x     = (const float*)d_in[0];  // [2048][1024]
  const float* w_qkv = (const float*)d_in[1];  // [1024][3072]
  const float* b_qkv = (const float*)d_in[2];  // [3072]
  const float* w_out = (const float*)d_in[3];  // [1024][1024]
  const float* b_out = (const float*)d_in[4];  // [1024]
  float* out = (float*)d_out;                  // [2048][1024] f32
  char* ws = (char*)d_ws;

  u16* xb    = (u16*)(ws);             // 2048*1024*2  = 4,194,304
  u16* wqkvT = (u16*)(ws + 4194304);   // 3072*1024*2  = 6,291,456
  u16* woutT = (u16*)(ws + 10485760);  // 1024*1024*2  = 2,097,152
  u16* qkv3  = (u16*)(ws + 12582912);  // 2048*3072*2  = 12,582,912
  u16* attnb = (u16*)(ws + 25165824);  // 2048*1024*2  = 4,194,304
  u16* vT    = (u16*)(ws + 29360128);  // 1024*2048*2  = 4,194,304
  u16* vTs   = (u16*)(ws + 33554432);  // 1024*64*2    = 131,072   (end 33,685,504)

  prep<<<2048, 256, 0, stream>>>(x, xb, w_qkv, wqkvT, w_out, woutT);
  gemm_qkv<<<768, 256, 0, stream>>>(xb, wqkvT, b_qkv, qkv3, vT, vTs, 1024);
  sattn<<<dim3(16, 32), 256, 0, stream>>>(qkv3, vT, vTs, attnb);
  gemm_out<<<512, 256, 0, stream>>>(attnb, woutT, b_out, out, 1024);
}

// Round 15
// 54.642 us; speedup vs baseline: 1.0073x; 1.0073x over previous
//
#include <hip/hip_runtime.h>

typedef unsigned short u16;
typedef __attribute__((ext_vector_type(8))) short bf16x8;
typedef __attribute__((ext_vector_type(4))) float f32x4;

__device__ __forceinline__ u16 f2bf(float f) {
  union { float f; unsigned u; } v; v.f = f;
  unsigned u = v.u;
  return (u16)((u + 0x7FFFu + ((u >> 16) & 1u)) >> 16);
}

__device__ __forceinline__ void gld16(const void* g, void* l) {
  __builtin_amdgcn_global_load_lds((const __attribute__((address_space(1))) void*)g,
                                   (__attribute__((address_space(3))) void*)l, 16, 0, 0);
}

// ---------------- fused prep: cvt x->bf16 | transpose+cvt w_qkv | w_out ----------------
__device__ __forceinline__ void tconv64(const float* __restrict__ in, u16* __restrict__ out,
                                        int R, int C, int bc, int br, float* t) {
  const int tid = threadIdx.x;
  const int c0 = bc * 64, r0 = br * 64;
  const int hi = tid >> 4, lo = tid & 15;
#pragma unroll
  for (int it = 0; it < 4; ++it) {
    int r = it * 16 + hi;
    float4 f = *(const float4*)&in[(size_t)(r0 + r) * C + c0 + lo * 4];
    float* tr = &t[r * 65 + lo * 4];
    tr[0] = f.x; tr[1] = f.y; tr[2] = f.z; tr[3] = f.w;
  }
  __syncthreads();
#pragma unroll
  for (int it = 0; it < 4; ++it) {
    int cc = it * 16 + hi;
    ushort4 o;
    o.x = f2bf(t[(lo * 4 + 0) * 65 + cc]);
    o.y = f2bf(t[(lo * 4 + 1) * 65 + cc]);
    o.z = f2bf(t[(lo * 4 + 2) * 65 + cc]);
    o.w = f2bf(t[(lo * 4 + 3) * 65 + cc]);
    *(ushort4*)&out[(size_t)(c0 + cc) * R + r0 + lo * 4] = o;
  }
}

__global__ __launch_bounds__(256) void prep(const float* __restrict__ x, u16* __restrict__ xb,
                                            const float* __restrict__ wq, u16* __restrict__ wqT,
                                            const float* __restrict__ wo, u16* __restrict__ woT) {
  __shared__ float t[64 * 65];
  int b = blockIdx.x;
  if (b < 1024) {
    int i = (b * 256 + threadIdx.x) * 8;
    float4 f0 = *(const float4*)(x + i);
    float4 f1 = *(const float4*)(x + i + 4);
    ushort4 r0, r1;
    r0.x = f2bf(f0.x); r0.y = f2bf(f0.y); r0.z = f2bf(f0.z); r0.w = f2bf(f0.w);
    r1.x = f2bf(f1.x); r1.y = f2bf(f1.y); r1.z = f2bf(f1.z); r1.w = f2bf(f1.w);
    *(ushort4*)(xb + i) = r0;
    *(ushort4*)(xb + i + 4) = r1;
  } else if (b < 1024 + 768) {
    int b2 = b - 1024;
    tconv64(wq, wqT, 1024, 3072, b2 % 48, b2 / 48, t);
  } else {
    int b3 = b - 1792;
    tconv64(wo, woT, 1024, 1024, b3 & 15, b3 >> 4, t);
  }
}

// ---- shared STAGE/COMPUTE macros for the dbuf GEMMs (BK=64, 4 waves 2x2) ----
#define GEMM_STAGE(As, Bs, A, BT, buf, kt, BM, BN, MT, NT)                        \
  {                                                                               \
    _Pragma("unroll")                                                             \
    for (int it = 0; it < MT; ++it) {                                             \
      int G = wv * (MT * 64) + it * 64 + lane;                                    \
      int r = G >> 3, g = G & 7, gs = g ^ (r & 7);                                \
      gld16(&A[(size_t)(m0 + r) * K + (kt) + gs * 8],                             \
            &As[buf][(wv * (MT * 64) + it * 64) * 8]);                            \
    }                                                                             \
    _Pragma("unroll")                                                             \
    for (int it = 0; it < NT; ++it) {                                             \
      int G = wv * (NT * 64) + it * 64 + lane;                                    \
      int r = G >> 3, g = G & 7, gs = g ^ (r & 7);                                \
      gld16(&BT[(size_t)(n0 + r) * K + (kt) + gs * 8],                            \
            &Bs[buf][(wv * (NT * 64) + it * 64) * 8]);                            \
    }                                                                             \
  }

#define GEMM_COMPUTE(As, Bs, buf, BM, BN, MT, NT)                                 \
  {                                                                               \
    _Pragma("unroll")                                                             \
    for (int ks = 0; ks < 2; ++ks) {                                              \
      bf16x8 av[MT], bv[NT];                                                      \
      _Pragma("unroll")                                                           \
      for (int m = 0; m < MT; ++m) {                                              \
        int r = wm * (BM / 2) + m * 16 + lr;                                      \
        av[m] = *(const bf16x8*)&As[buf][r * 64 + (((ks * 4 + lg) ^ (r & 7)) * 8)]; \
      }                                                                           \
      _Pragma("unroll")                                                           \
      for (int n = 0; n < NT; ++n) {                                              \
        int r = wn * (BN / 2) + n * 16 + lr;                                      \
        bv[n] = *(const bf16x8*)&Bs[buf][r * 64 + (((ks * 4 + lg) ^ (r & 7)) * 8)]; \
      }                                                                           \
      _Pragma("unroll")                                                           \
      for (int m = 0; m < MT; ++m)                                                \
        _Pragma("unroll")                                                         \
        for (int n = 0; n < NT; ++n)                                              \
          acc[m][n] = __builtin_amdgcn_mfma_f32_16x16x32_bf16(av[m], bv[n],       \
                                                              acc[m][n], 0, 0, 0); \
    }                                                                             \
  }

// ---------------- QKV GEMM (128x64) with fused V-transpose epilogue -----------
__global__ __launch_bounds__(256) void gemm_qkv(const u16* __restrict__ A,
                                                const u16* __restrict__ BT,
                                                const float* __restrict__ bias,
                                                u16* __restrict__ qkv3,
                                                u16* __restrict__ vT,
                                                u16* __restrict__ vTs,
                                                int K) {
  constexpr int BM = 128, BN = 64, MT = 4, NT = 2;
  __shared__ u16 As[2][BM * 64];
  __shared__ u16 Bs[2][BN * 64];
  const int tid = threadIdx.x;
  const int lane = tid & 63, wv = tid >> 6;
  const int lr = lane & 15, lg = lane >> 4;
  const int wm = wv >> 1, wn = wv & 1;
  const int m0 = blockIdx.y * BM, n0 = blockIdx.x * BN;

  f32x4 acc[MT][NT] = {};

  GEMM_STAGE(As, Bs, A, BT, 0, 0, BM, BN, MT, NT);
  __syncthreads();
  int cur = 0;
  for (int kt = 64; kt < K; kt += 64) {
    GEMM_STAGE(As, Bs, A, BT, cur ^ 1, kt, BM, BN, MT, NT);
    GEMM_COMPUTE(As, Bs, cur, BM, BN, MT, NT);
    __syncthreads();
    cur ^= 1;
  }
  GEMM_COMPUTE(As, Bs, cur, BM, BN, MT, NT);

  if (n0 < 2048) {
#pragma unroll
    for (int m = 0; m < MT; ++m)
#pragma unroll
      for (int n = 0; n < NT; ++n) {
        int col = n0 + wn * 32 + n * 16 + lr;
        float bcol = bias[col];
#pragma unroll
        for (int qq = 0; qq < 4; ++qq) {
          int row = m0 + wm * 64 + m * 16 + 4 * lg + qq;
          qkv3[(size_t)row * 3072 + col] = f2bf(acc[m][n][qq] + bcol);
        }
      }
  } else {
    __syncthreads();               // all LDS reads of As/Bs done; reuse as T
    u16* T = &As[0][0];            // [64][132] bf16 (pad 132 spreads banks)
#pragma unroll
    for (int m = 0; m < MT; ++m)
#pragma unroll
      for (int n = 0; n < NT; ++n) {
        int col = wn * 32 + n * 16 + lr;
        float bcol = bias[n0 + col];
#pragma unroll
        for (int qq = 0; qq < 4; ++qq) {
          int row = wm * 64 + m * 16 + 4 * lg + qq;
          T[col * 132 + row] = f2bf(acc[m][n][qq] + bcol);
        }
      }
    __syncthreads();
    const int dgb = n0 - 2048;
#pragma unroll
    for (int c = wv; c < 64; c += 4) {
      uint val = (uint)T[c * 132 + lane * 2] | ((uint)T[c * 132 + lane * 2 + 1] << 16);
      *(uint*)&vT[(size_t)(dgb + c) * 2048 + m0 + lane * 2] = val;
    }
    {
      int rr = tid >> 6, c = tid & 63;
      vTs[(size_t)(dgb + c) * 64 + (m0 >> 5) + rr] = T[c * 132 + rr * 32];
    }
  }
}

// ---------------- out projection GEMM (64x64, f32 out, vectorized store) ------
// Epilogue change vs R13: acc+bias goes through an LDS f32 transpose buffer
// (reusing dead As) and stores as float4 — each 16-lane group writes 256 B
// contiguous (was 16 scalar dword stores/lane in scattered 64 B segments).
__global__ __launch_bounds__(256) void gemm_out(const u16* __restrict__ A,
                                                const u16* __restrict__ BT,
                                                const float* __restrict__ bias,
                                                float* __restrict__ Cp,
                                                int K) {
  constexpr int BM = 64, BN = 64, MT = 2, NT = 2;
  __shared__ u16 As[2][BM * 64];
  __shared__ u16 Bs[2][BN * 64];
  const int tid = threadIdx.x;
  const int lane = tid & 63, wv = tid >> 6;
  const int lr = lane & 15, lg = lane >> 4;
  const int wm = wv >> 1, wn = wv & 1;
  const int m0 = blockIdx.y * BM, n0 = blockIdx.x * BN;

  f32x4 acc[MT][NT] = {};

  GEMM_STAGE(As, Bs, A, BT, 0, 0, BM, BN, MT, NT);
  __syncthreads();
  int cur = 0;
  for (int kt = 64; kt < K; kt += 64) {
    GEMM_STAGE(As, Bs, A, BT, cur ^ 1, kt, BM, BN, MT, NT);
    GEMM_COMPUTE(As, Bs, cur, BM, BN, MT, NT);
    __syncthreads();
    cur ^= 1;
  }
  GEMM_COMPUTE(As, Bs, cur, BM, BN, MT, NT);

  __syncthreads();                       // LDS reads done; reuse As as f32 T[64][65]
  float* T = (float*)&As[0][0];          // 64*65*4 = 16.6 KB <= 32 KB
#pragma unroll
  for (int m = 0; m < MT; ++m)
#pragma unroll
    for (int n = 0; n < NT; ++n) {
      int col = wn * 32 + n * 16 + lr;
      float bcol = bias[n0 + col];
#pragma unroll
      for (int qq = 0; qq < 4; ++qq) {
        int row = wm * 32 + m * 16 + 4 * lg + qq;
        T[row * 65 + col] = acc[m][n][qq] + bcol;
      }
    }
  __syncthreads();
#pragma unroll
  for (int pass = 0; pass < 4; ++pass) {
    int row = pass * 16 + (tid >> 4);
    int c4 = (tid & 15) * 4;
    const float* tr = &T[row * 65 + c4];
    float4 v;
    v.x = tr[0]; v.y = tr[1]; v.z = tr[2]; v.w = tr[3];
    *(float4*)&Cp[(size_t)(m0 + row) * 1024 + n0 + c4] = v;
  }
}

// ---------------- sparse attention: (head, 64-row) blocks, staged K/V ----------
// (unchanged from R13: P aliases K's LDS -> 64 KB, 2 blocks/CU)
__global__ __launch_bounds__(256) void sattn(const u16* __restrict__ qkv,
                                             const u16* __restrict__ vT,
                                             const u16* __restrict__ vTs,
                                             u16* __restrict__ ao) {
  const int h = blockIdx.x;
  const int i0b = blockIdx.y * 64;
  const int ws = i0b - 64;
  const int tid = threadIdx.x;
  const int lane = tid & 63, wv = tid >> 6;
  const int lr = lane & 15, lg = lane >> 4;

  __shared__ __attribute__((aligned(16))) u16 KP[256 * 64];   // 32 KB: K, then P
  __shared__ __attribute__((aligned(16))) u16 Vl[64 * 256];   // 32 KB

#pragma unroll
  for (int it = 0; it < 8; ++it) {
    {
      int ck = wv * 8 + it;
      int c = 8 * ck + (lane >> 3);
      int g = lane & 7, gs = g ^ (c & 7);
      int j = (c < 192) ? (ws + c) : ((c - 192) << 5);
      j = j < 0 ? 0 : (j > 2047 ? 2047 : j);
      gld16(&qkv[(size_t)j * 3072 + 1024 + h * 64 + gs * 8], &KP[ck * 512]);
    }
    {
      int tv = wv * 8 + it;
      int d = 2 * tv + (lane >> 5);
      int g = lane & 31, gs = g ^ (d & 7);
      const u16* src;
      if (gs < 24) {
        int c0 = ws + gs * 8;
        c0 = c0 < 0 ? 0 : (c0 > 2040 ? 2040 : c0);
        src = &vT[(size_t)(h * 64 + d) * 2048 + c0];
      } else {
        src = &vTs[(size_t)(h * 64 + d) * 64 + (gs - 24) * 8];
      }
      gld16(src, &Vl[tv * 512]);
    }
  }
  __syncthreads();

  const int i0 = i0b + wv * 16;
  const u16* qp = &qkv[(size_t)(i0 + lr) * 3072 + h * 64 + lg * 8];
  bf16x8 qa0 = *(const bf16x8*)qp;
  bf16x8 qa1 = *(const bf16x8*)(qp + 32);

  f32x4 sc[16];
#pragma unroll
  for (int n = 0; n < 16; ++n) {
    int c = n * 16 + lr;
    bf16x8 k0 = *(const bf16x8*)&KP[c * 64 + ((lg ^ (c & 7)) * 8)];
    bf16x8 k1 = *(const bf16x8*)&KP[c * 64 + (((4 + lg) ^ (c & 7)) * 8)];
    f32x4 a = {0.f, 0.f, 0.f, 0.f};
    a = __builtin_amdgcn_mfma_f32_16x16x32_bf16(qa0, k0, a, 0, 0, 0);
    a = __builtin_amdgcn_mfma_f32_16x16x32_bf16(qa1, k1, a, 0, 0, 0);
    sc[n] = a;
  }

  float mx[4] = {-1e30f, -1e30f, -1e30f, -1e30f};
#pragma unroll
  for (int n = 0; n < 16; ++n) {
    int c = n * 16 + lr;
    int jw = ws + c;
    int js = (c - 192) << 5;
    bool isw = c < 192;
#pragma unroll
    for (int qq = 0; qq < 4; ++qq) {
      int i = i0 + 4 * lg + qq;
      bool ok;
      if (isw) {
        int dd = i - jw; dd = dd < 0 ? -dd : dd;
        ok = (jw >= 0) && (jw < 2048) && ((dd <= 64) || ((jw & 31) == 0));
      } else {
        ok = (js < ws) || (js >= ws + 192);
      }
      float v = ok ? sc[n][qq] * 0.125f : -1e30f;
      sc[n][qq] = v;
      mx[qq] = fmaxf(mx[qq], v);
    }
  }
#pragma unroll
  for (int qq = 0; qq < 4; ++qq) {
    float v = mx[qq];
    v = fmaxf(v, __shfl_xor(v, 1));
    v = fmaxf(v, __shfl_xor(v, 2));
    v = fmaxf(v, __shfl_xor(v, 4));
    v = fmaxf(v, __shfl_xor(v, 8));
    mx[qq] = v;
  }

  __syncthreads();   // all waves finished reading K from KP -> safe to overwrite with P

  char* pw = (char*)KP + wv * 8192;
  float sm[4] = {0.f, 0.f, 0.f, 0.f};
#pragma unroll
  for (int n = 0; n < 16; ++n) {
#pragma unroll
    for (int qq = 0; qq < 4; ++qq) {
      float p = __expf(sc[n][qq] - mx[qq]);
      sm[qq] += p;
      int r = 4 * lg + qq, c = n * 16 + lr;
      *(u16*)(pw + r * 512 + ((2 * c) ^ ((r & 7) << 4))) = f2bf(p);
    }
  }
#pragma unroll
  for (int qq = 0; qq < 4; ++qq) {
    float s = sm[qq];
    s += __shfl_xor(s, 1);
    s += __shfl_xor(s, 2);
    s += __shfl_xor(s, 4);
    s += __shfl_xor(s, 8);
    sm[qq] = s;
  }

  f32x4 ov[4] = {{0.f,0.f,0.f,0.f},{0.f,0.f,0.f,0.f},{0.f,0.f,0.f,0.f},{0.f,0.f,0.f,0.f}};
#pragma unroll
  for (int ksb = 0; ksb < 8; ++ksb) {
    bf16x8 pa = *(const bf16x8*)(pw + lr * 512 + ((ksb * 64 + lg * 16) ^ ((lr & 7) << 4)));
#pragma unroll
    for (int n = 0; n < 4; ++n) {
      int d = n * 16 + lr;
      bf16x8 vb = *(const bf16x8*)&Vl[d * 256 + (((ksb * 4 + lg) ^ (d & 7)) * 8)];
      ov[n] = __builtin_amdgcn_mfma_f32_16x16x32_bf16(pa, vb, ov[n], 0, 0, 0);
    }
  }

#pragma unroll
  for (int qq = 0; qq < 4; ++qq) {
    float inv = 1.0f / sm[qq];
    int row = i0 + 4 * lg + qq;
#pragma unroll
    for (int n = 0; n < 4; ++n)
      ao[(size_t)row * 1024 + h * 64 + n * 16 + lr] = f2bf(ov[n][qq] * inv);
  }
}

// ---------------- launch ----------------
extern "C" void kernel_launch(void* const* d_in, const int* in_sizes, int n_in,
                              void* d_out, int out_size, void* d_ws, size_t ws_size,
                              hipStream_t stream) {
  (void)in_sizes; (void)n_in; (void)out_size; (void)ws_size;
  const float* x     = (const float*)d_in[0];  // [2048][1024]
  const float* w_qkv = (const float*)d_in[1];  // [1024][3072]
  const float* b_qkv = (const float*)d_in[2];  // [3072]
  const float* w_out = (const float*)d_in[3];  // [1024][1024]
  const float* b_out = (const float*)d_in[4];  // [1024]
  float* out = (float*)d_out;                  // [2048][1024] f32
  char* ws = (char*)d_ws;

  u16* xb    = (u16*)(ws);             // 2048*1024*2  = 4,194,304
  u16* wqkvT = (u16*)(ws + 4194304);   // 3072*1024*2  = 6,291,456
  u16* woutT = (u16*)(ws + 10485760);  // 1024*1024*2  = 2,097,152
  u16* qkv3  = (u16*)(ws + 12582912);  // 2048*3072*2  = 12,582,912
  u16* attnb = (u16*)(ws + 25165824);  // 2048*1024*2  = 4,194,304
  u16* vT    = (u16*)(ws + 29360128);  // 1024*2048*2  = 4,194,304
  u16* vTs   = (u16*)(ws + 33554432);  // 1024*64*2    = 131,072   (end 33,685,504)

  prep<<<2048, 256, 0, stream>>>(x, xb, w_qkv, wqkvT, w_out, woutT);
  gemm_qkv<<<dim3(3072 / 64, 2048 / 128), 256, 0, stream>>>(xb, wqkvT, b_qkv, qkv3, vT, vTs,
                                                            1024);
  sattn<<<dim3(16, 32), 256, 0, stream>>>(qkv3, vT, vTs, attnb);
  gemm_out<<<dim3(1024 / 64, 2048 / 64), 256, 0, stream>>>(attnb, woutT, b_out, out, 1024);
}

// Round 16
// 53.889 us; speedup vs baseline: 1.0213x; 1.0140x over previous
//
#include <hip/hip_runtime.h>

typedef unsigned short u16;
typedef __attribute__((ext_vector_type(8))) short bf16x8;
typedef __attribute__((ext_vector_type(4))) float f32x4;

__device__ __forceinline__ u16 f2bf(float f) {
  union { float f; unsigned u; } v; v.f = f;
  unsigned u = v.u;
  return (u16)((u + 0x7FFFu + ((u >> 16) & 1u)) >> 16);
}

__device__ __forceinline__ void gld16(const void* g, void* l) {
  __builtin_amdgcn_global_load_lds((const __attribute__((address_space(1))) void*)g,
                                   (__attribute__((address_space(3))) void*)l, 16, 0, 0);
}

// ---------------- fused prep: cvt x->bf16 | transpose+cvt w_qkv | w_out ----------------
__device__ __forceinline__ void tconv64(const float* __restrict__ in, u16* __restrict__ out,
                                        int R, int C, int bc, int br, float* t) {
  const int tid = threadIdx.x;
  const int c0 = bc * 64, r0 = br * 64;
  const int hi = tid >> 4, lo = tid & 15;
#pragma unroll
  for (int it = 0; it < 4; ++it) {
    int r = it * 16 + hi;
    float4 f = *(const float4*)&in[(size_t)(r0 + r) * C + c0 + lo * 4];
    float* tr = &t[r * 65 + lo * 4];
    tr[0] = f.x; tr[1] = f.y; tr[2] = f.z; tr[3] = f.w;
  }
  __syncthreads();
#pragma unroll
  for (int it = 0; it < 4; ++it) {
    int cc = it * 16 + hi;
    ushort4 o;
    o.x = f2bf(t[(lo * 4 + 0) * 65 + cc]);
    o.y = f2bf(t[(lo * 4 + 1) * 65 + cc]);
    o.z = f2bf(t[(lo * 4 + 2) * 65 + cc]);
    o.w = f2bf(t[(lo * 4 + 3) * 65 + cc]);
    *(ushort4*)&out[(size_t)(c0 + cc) * R + r0 + lo * 4] = o;
  }
}

__global__ __launch_bounds__(256) void prep(const float* __restrict__ x, u16* __restrict__ xb,
                                            const float* __restrict__ wq, u16* __restrict__ wqT,
                                            const float* __restrict__ wo, u16* __restrict__ woT) {
  __shared__ float t[64 * 65];
  int b = blockIdx.x;
  if (b < 1024) {
    int i = (b * 256 + threadIdx.x) * 8;
    float4 f0 = *(const float4*)(x + i);
    float4 f1 = *(const float4*)(x + i + 4);
    ushort4 r0, r1;
    r0.x = f2bf(f0.x); r0.y = f2bf(f0.y); r0.z = f2bf(f0.z); r0.w = f2bf(f0.w);
    r1.x = f2bf(f1.x); r1.y = f2bf(f1.y); r1.z = f2bf(f1.z); r1.w = f2bf(f1.w);
    *(ushort4*)(xb + i) = r0;
    *(ushort4*)(xb + i + 4) = r1;
  } else if (b < 1024 + 768) {
    int b2 = b - 1024;
    tconv64(wq, wqT, 1024, 3072, b2 % 48, b2 / 48, t);
  } else {
    int b3 = b - 1792;
    tconv64(wo, woT, 1024, 1024, b3 & 15, b3 >> 4, t);
  }
}

// ---- shared STAGE/COMPUTE macros for the dbuf GEMMs (BK=64, 4 waves 2x2) ----
#define GEMM_STAGE(As, Bs, A, BT, buf, kt, BM, BN, MT, NT)                        \
  {                                                                               \
    _Pragma("unroll")                                                             \
    for (int it = 0; it < MT; ++it) {                                             \
      int G = wv * (MT * 64) + it * 64 + lane;                                    \
      int r = G >> 3, g = G & 7, gs = g ^ (r & 7);                                \
      gld16(&A[(size_t)(m0 + r) * K + (kt) + gs * 8],                             \
            &As[buf][(wv * (MT * 64) + it * 64) * 8]);                            \
    }                                                                             \
    _Pragma("unroll")                                                             \
    for (int it = 0; it < NT; ++it) {                                             \
      int G = wv * (NT * 64) + it * 64 + lane;                                    \
      int r = G >> 3, g = G & 7, gs = g ^ (r & 7);                                \
      gld16(&BT[(size_t)(n0 + r) * K + (kt) + gs * 8],                            \
            &Bs[buf][(wv * (NT * 64) + it * 64) * 8]);                            \
    }                                                                             \
  }

#define GEMM_COMPUTE(As, Bs, buf, BM, BN, MT, NT)                                 \
  {                                                                               \
    _Pragma("unroll")                                                             \
    for (int ks = 0; ks < 2; ++ks) {                                              \
      bf16x8 av[MT], bv[NT];                                                      \
      _Pragma("unroll")                                                           \
      for (int m = 0; m < MT; ++m) {                                              \
        int r = wm * (BM / 2) + m * 16 + lr;                                      \
        av[m] = *(const bf16x8*)&As[buf][r * 64 + (((ks * 4 + lg) ^ (r & 7)) * 8)]; \
      }                                                                           \
      _Pragma("unroll")                                                           \
      for (int n = 0; n < NT; ++n) {                                              \
        int r = wn * (BN / 2) + n * 16 + lr;                                      \
        bv[n] = *(const bf16x8*)&Bs[buf][r * 64 + (((ks * 4 + lg) ^ (r & 7)) * 8)]; \
      }                                                                           \
      _Pragma("unroll")                                                           \
      for (int m = 0; m < MT; ++m)                                                \
        _Pragma("unroll")                                                         \
        for (int n = 0; n < NT; ++n)                                              \
          acc[m][n] = __builtin_amdgcn_mfma_f32_16x16x32_bf16(av[m], bv[n],       \
                                                              acc[m][n], 0, 0, 0); \
    }                                                                             \
  }

// ---------------- QKV GEMM (128x64) with fused V-transpose epilogue -----------
__global__ __launch_bounds__(256) void gemm_qkv(const u16* __restrict__ A,
                                                const u16* __restrict__ BT,
                                                const float* __restrict__ bias,
                                                u16* __restrict__ qkv3,
                                                u16* __restrict__ vT,
                                                u16* __restrict__ vTs,
                                                int K) {
  constexpr int BM = 128, BN = 64, MT = 4, NT = 2;
  __shared__ u16 As[2][BM * 64];
  __shared__ u16 Bs[2][BN * 64];
  const int tid = threadIdx.x;
  const int lane = tid & 63, wv = tid >> 6;
  const int lr = lane & 15, lg = lane >> 4;
  const int wm = wv >> 1, wn = wv & 1;
  const int m0 = blockIdx.y * BM, n0 = blockIdx.x * BN;

  f32x4 acc[MT][NT] = {};

  GEMM_STAGE(As, Bs, A, BT, 0, 0, BM, BN, MT, NT);
  __syncthreads();
  int cur = 0;
  for (int kt = 64; kt < K; kt += 64) {
    GEMM_STAGE(As, Bs, A, BT, cur ^ 1, kt, BM, BN, MT, NT);
    GEMM_COMPUTE(As, Bs, cur, BM, BN, MT, NT);
    __syncthreads();
    cur ^= 1;
  }
  GEMM_COMPUTE(As, Bs, cur, BM, BN, MT, NT);

  if (n0 < 2048) {
#pragma unroll
    for (int m = 0; m < MT; ++m)
#pragma unroll
      for (int n = 0; n < NT; ++n) {
        int col = n0 + wn * 32 + n * 16 + lr;
        float bcol = bias[col];
#pragma unroll
        for (int qq = 0; qq < 4; ++qq) {
          int row = m0 + wm * 64 + m * 16 + 4 * lg + qq;
          qkv3[(size_t)row * 3072 + col] = f2bf(acc[m][n][qq] + bcol);
        }
      }
  } else {
    __syncthreads();               // all LDS reads of As/Bs done; reuse as T
    u16* T = &As[0][0];            // [64][132] bf16 (pad 132 spreads banks)
#pragma unroll
    for (int m = 0; m < MT; ++m)
#pragma unroll
      for (int n = 0; n < NT; ++n) {
        int col = wn * 32 + n * 16 + lr;
        float bcol = bias[n0 + col];
#pragma unroll
        for (int qq = 0; qq < 4; ++qq) {
          int row = wm * 64 + m * 16 + 4 * lg + qq;
          T[col * 132 + row] = f2bf(acc[m][n][qq] + bcol);
        }
      }
    __syncthreads();
    const int dgb = n0 - 2048;
#pragma unroll
    for (int c = wv; c < 64; c += 4) {
      uint val = (uint)T[c * 132 + lane * 2] | ((uint)T[c * 132 + lane * 2 + 1] << 16);
      *(uint*)&vT[(size_t)(dgb + c) * 2048 + m0 + lane * 2] = val;
    }
    {
      int rr = tid >> 6, c = tid & 63;
      vTs[(size_t)(dgb + c) * 64 + (m0 >> 5) + rr] = T[c * 132 + rr * 32];
    }
  }
}

// ---------------- out projection GEMM (64x32, f32 out) ----------------
// Isolated change vs R13: tile 64x64 -> 64x32 (MT=2, NT=1), grid 1024 blocks
// = 4 blocks/CU (was 512 = 2/CU, grid-limited). Occupancy-over-traffic trade,
// same mechanism as R13's sattn win. LDS 24 KB dbuf.
__global__ __launch_bounds__(256) void gemm_out(const u16* __restrict__ A,
                                                const u16* __restrict__ BT,
                                                const float* __restrict__ bias,
                                                float* __restrict__ Cp,
                                                int K) {
  constexpr int BM = 64, BN = 32, MT = 2, NT = 1;
  __shared__ u16 As[2][BM * 64];
  __shared__ u16 Bs[2][BN * 64];
  const int tid = threadIdx.x;
  const int lane = tid & 63, wv = tid >> 6;
  const int lr = lane & 15, lg = lane >> 4;
  const int wm = wv >> 1, wn = wv & 1;
  const int m0 = blockIdx.y * BM, n0 = blockIdx.x * BN;

  f32x4 acc[MT][NT] = {};

  GEMM_STAGE(As, Bs, A, BT, 0, 0, BM, BN, MT, NT);
  __syncthreads();
  int cur = 0;
  for (int kt = 64; kt < K; kt += 64) {
    GEMM_STAGE(As, Bs, A, BT, cur ^ 1, kt, BM, BN, MT, NT);
    GEMM_COMPUTE(As, Bs, cur, BM, BN, MT, NT);
    __syncthreads();
    cur ^= 1;
  }
  GEMM_COMPUTE(As, Bs, cur, BM, BN, MT, NT);

#pragma unroll
  for (int m = 0; m < MT; ++m) {
    int col = n0 + wn * 16 + lr;
    float bcol = bias[col];
#pragma unroll
    for (int qq = 0; qq < 4; ++qq) {
      int row = m0 + wm * 32 + m * 16 + 4 * lg + qq;
      Cp[(size_t)row * 1024 + col] = acc[m][0][qq] + bcol;
    }
  }
}

// ---------------- sparse attention: (head, 64-row) blocks, staged K/V ----------
// (unchanged from R13: P aliases K's LDS -> 64 KB, 2 blocks/CU)
__global__ __launch_bounds__(256) void sattn(const u16* __restrict__ qkv,
                                             const u16* __restrict__ vT,
                                             const u16* __restrict__ vTs,
                                             u16* __restrict__ ao) {
  const int h = blockIdx.x;
  const int i0b = blockIdx.y * 64;
  const int ws = i0b - 64;
  const int tid = threadIdx.x;
  const int lane = tid & 63, wv = tid >> 6;
  const int lr = lane & 15, lg = lane >> 4;

  __shared__ __attribute__((aligned(16))) u16 KP[256 * 64];   // 32 KB: K, then P
  __shared__ __attribute__((aligned(16))) u16 Vl[64 * 256];   // 32 KB

#pragma unroll
  for (int it = 0; it < 8; ++it) {
    {
      int ck = wv * 8 + it;
      int c = 8 * ck + (lane >> 3);
      int g = lane & 7, gs = g ^ (c & 7);
      int j = (c < 192) ? (ws + c) : ((c - 192) << 5);
      j = j < 0 ? 0 : (j > 2047 ? 2047 : j);
      gld16(&qkv[(size_t)j * 3072 + 1024 + h * 64 + gs * 8], &KP[ck * 512]);
    }
    {
      int tv = wv * 8 + it;
      int d = 2 * tv + (lane >> 5);
      int g = lane & 31, gs = g ^ (d & 7);
      const u16* src;
      if (gs < 24) {
        int c0 = ws + gs * 8;
        c0 = c0 < 0 ? 0 : (c0 > 2040 ? 2040 : c0);
        src = &vT[(size_t)(h * 64 + d) * 2048 + c0];
      } else {
        src = &vTs[(size_t)(h * 64 + d) * 64 + (gs - 24) * 8];
      }
      gld16(src, &Vl[tv * 512]);
    }
  }
  __syncthreads();

  const int i0 = i0b + wv * 16;
  const u16* qp = &qkv[(size_t)(i0 + lr) * 3072 + h * 64 + lg * 8];
  bf16x8 qa0 = *(const bf16x8*)qp;
  bf16x8 qa1 = *(const bf16x8*)(qp + 32);

  f32x4 sc[16];
#pragma unroll
  for (int n = 0; n < 16; ++n) {
    int c = n * 16 + lr;
    bf16x8 k0 = *(const bf16x8*)&KP[c * 64 + ((lg ^ (c & 7)) * 8)];
    bf16x8 k1 = *(const bf16x8*)&KP[c * 64 + (((4 + lg) ^ (c & 7)) * 8)];
    f32x4 a = {0.f, 0.f, 0.f, 0.f};
    a = __builtin_amdgcn_mfma_f32_16x16x32_bf16(qa0, k0, a, 0, 0, 0);
    a = __builtin_amdgcn_mfma_f32_16x16x32_bf16(qa1, k1, a, 0, 0, 0);
    sc[n] = a;
  }

  float mx[4] = {-1e30f, -1e30f, -1e30f, -1e30f};
#pragma unroll
  for (int n = 0; n < 16; ++n) {
    int c = n * 16 + lr;
    int jw = ws + c;
    int js = (c - 192) << 5;
    bool isw = c < 192;
#pragma unroll
    for (int qq = 0; qq < 4; ++qq) {
      int i = i0 + 4 * lg + qq;
      bool ok;
      if (isw) {
        int dd = i - jw; dd = dd < 0 ? -dd : dd;
        ok = (jw >= 0) && (jw < 2048) && ((dd <= 64) || ((jw & 31) == 0));
      } else {
        ok = (js < ws) || (js >= ws + 192);
      }
      float v = ok ? sc[n][qq] * 0.125f : -1e30f;
      sc[n][qq] = v;
      mx[qq] = fmaxf(mx[qq], v);
    }
  }
#pragma unroll
  for (int qq = 0; qq < 4; ++qq) {
    float v = mx[qq];
    v = fmaxf(v, __shfl_xor(v, 1));
    v = fmaxf(v, __shfl_xor(v, 2));
    v = fmaxf(v, __shfl_xor(v, 4));
    v = fmaxf(v, __shfl_xor(v, 8));
    mx[qq] = v;
  }

  __syncthreads();   // all waves finished reading K from KP -> safe to overwrite with P

  char* pw = (char*)KP + wv * 8192;
  float sm[4] = {0.f, 0.f, 0.f, 0.f};
#pragma unroll
  for (int n = 0; n < 16; ++n) {
#pragma unroll
    for (int qq = 0; qq < 4; ++qq) {
      float p = __expf(sc[n][qq] - mx[qq]);
      sm[qq] += p;
      int r = 4 * lg + qq, c = n * 16 + lr;
      *(u16*)(pw + r * 512 + ((2 * c) ^ ((r & 7) << 4))) = f2bf(p);
    }
  }
#pragma unroll
  for (int qq = 0; qq < 4; ++qq) {
    float s = sm[qq];
    s += __shfl_xor(s, 1);
    s += __shfl_xor(s, 2);
    s += __shfl_xor(s, 4);
    s += __shfl_xor(s, 8);
    sm[qq] = s;
  }

  f32x4 ov[4] = {{0.f,0.f,0.f,0.f},{0.f,0.f,0.f,0.f},{0.f,0.f,0.f,0.f},{0.f,0.f,0.f,0.f}};
#pragma unroll
  for (int ksb = 0; ksb < 8; ++ksb) {
    bf16x8 pa = *(const bf16x8*)(pw + lr * 512 + ((ksb * 64 + lg * 16) ^ ((lr & 7) << 4)));
#pragma unroll
    for (int n = 0; n < 4; ++n) {
      int d = n * 16 + lr;
      bf16x8 vb = *(const bf16x8*)&Vl[d * 256 + (((ksb * 4 + lg) ^ (d & 7)) * 8)];
      ov[n] = __builtin_amdgcn_mfma_f32_16x16x32_bf16(pa, vb, ov[n], 0, 0, 0);
    }
  }

#pragma unroll
  for (int qq = 0; qq < 4; ++qq) {
    float inv = 1.0f / sm[qq];
    int row = i0 + 4 * lg + qq;
#pragma unroll
    for (int n = 0; n < 4; ++n)
      ao[(size_t)row * 1024 + h * 64 + n * 16 + lr] = f2bf(ov[n][qq] * inv);
  }
}

// ---------------- launch ----------------
extern "C" void kernel_launch(void* const* d_in, const int* in_sizes, int n_in,
                              void* d_out, int out_size, void* d_ws, size_t ws_size,
                              hipStream_t stream) {
  (void)in_sizes; (void)n_in; (void)out_size; (void)ws_size;
  const float* x     = (const float*)d_in[0];  // [2048][1024]
  const float* w_qkv = (const float*)d_in[1];  // [1024][3072]
  const float* b_qkv = (const float*)d_in[2];  // [3072]
  const float* w_out = (const float*)d_in[3];  // [1024][1024]
  const float* b_out = (const float*)d_in[4];  // [1024]
  float* out = (float*)d_out;                  // [2048][1024] f32
  char* ws = (char*)d_ws;

  u16* xb    = (u16*)(ws);             // 2048*1024*2  = 4,194,304
  u16* wqkvT = (u16*)(ws + 4194304);   // 3072*1024*2  = 6,291,456
  u16* woutT = (u16*)(ws + 10485760);  // 1024*1024*2  = 2,097,152
  u16* qkv3  = (u16*)(ws + 12582912);  // 2048*3072*2  = 12,582,912
  u16* attnb = (u16*)(ws + 25165824);  // 2048*1024*2  = 4,194,304
  u16* vT    = (u16*)(ws + 29360128);  // 1024*2048*2  = 4,194,304
  u16* vTs   = (u16*)(ws + 33554432);  // 1024*64*2    = 131,072   (end 33,685,504)

  prep<<<2048, 256, 0, stream>>>(x, xb, w_qkv, wqkvT, w_out, woutT);
  gemm_qkv<<<dim3(3072 / 64, 2048 / 128), 256, 0, stream>>>(xb, wqkvT, b_qkv, qkv3, vT, vTs,
                                                            1024);
  sattn<<<dim3(16, 32), 256, 0, stream>>>(qkv3, vT, vTs, attnb);
  gemm_out<<<dim3(1024 / 32, 2048 / 64), 256, 0, stream>>>(attnb, woutT, b_out, out, 1024);
}